// Round 1
// baseline (343.730 us; speedup 1.0000x reference)
//
#include <hip/hip_runtime.h>
#include <math.h>

// Problem constants (B,S,D fixed by the reference harness)
#define BB 32
#define SS 2048
#define DD 1024
#define EPSF 1e-7f

// ---------------------------------------------------------------------------
// Kernel 1: proj[b,e] = sum_d y[b,d] * M[e,d]
// One wave (64 lanes) per (b,e). 32768 waves total.
// M row (4 KB) re-read 32x but M is 4 MB -> lives in L2/L3.
// ---------------------------------------------------------------------------
__global__ __launch_bounds__(256) void proj_kernel(const float* __restrict__ y,
                                                   const float* __restrict__ M,
                                                   float* __restrict__ proj) {
    const int wave = (blockIdx.x * 256 + threadIdx.x) >> 6;   // 0..32767
    const int lane = threadIdx.x & 63;
    const int b = wave >> 10;        // / 1024
    const int e = wave & 1023;

    const float4* __restrict__ Mrow = (const float4*)(M + (size_t)e * DD);
    const float4* __restrict__ yrow = (const float4*)(y + (size_t)b * DD);

    float acc = 0.f;
#pragma unroll
    for (int k = 0; k < 4; ++k) {
        const int idx = lane + 64 * k;       // 256 float4 per 1024-row
        const float4 m  = Mrow[idx];
        const float4 yy = yrow[idx];
        acc += m.x * yy.x + m.y * yy.y + m.z * yy.z + m.w * yy.w;
    }
#pragma unroll
    for (int off = 32; off >= 1; off >>= 1)
        acc += __shfl_xor(acc, off, 64);

    if (lane == 0) proj[wave] = acc;         // proj laid out [b][e]
}

// ---------------------------------------------------------------------------
// Kernel 2: t[b,s] = mask ? exp(tanh(sum_d x[b,s,d]*proj[b,d])) : 0
// One wave per (b,s). Masked rows skip the 4 KB x read entirely (~halves HBM).
// Writes unnormalized scores directly into d_out.
// ---------------------------------------------------------------------------
__global__ __launch_bounds__(256) void score_kernel(const float* __restrict__ x,
                                                    const int* __restrict__ mask,
                                                    const float* __restrict__ proj,
                                                    float* __restrict__ t) {
    const int wave = (blockIdx.x * 256 + threadIdx.x) >> 6;   // 0..65535
    const int lane = threadIdx.x & 63;
    const int b = wave >> 11;        // / 2048
    const int s = wave & 2047;

    const int m = mask[(size_t)b * SS + s];
    if (m == 0) {
        if (lane == 0) t[(size_t)b * SS + s] = 0.f;
        return;
    }

    const float4* __restrict__ xr = (const float4*)(x + ((size_t)b * SS + s) * DD);
    const float4* __restrict__ pr = (const float4*)(proj + (size_t)b * DD);

    float acc = 0.f;
#pragma unroll
    for (int k = 0; k < 4; ++k) {
        const int idx = lane + 64 * k;
        const float4 xv = xr[idx];
        const float4 pv = pr[idx];
        acc += xv.x * pv.x + xv.y * pv.y + xv.z * pv.z + xv.w * pv.w;
    }
#pragma unroll
    for (int off = 32; off >= 1; off >>= 1)
        acc += __shfl_xor(acc, off, 64);

    if (lane == 0) t[(size_t)b * SS + s] = expf(tanhf(acc));
}

// ---------------------------------------------------------------------------
// Kernel 3: in-place normalize: out[b,s] /= (sum_s out[b,s] + EPS)
// One block (256 threads) per batch; 8 values/thread held in registers.
// ---------------------------------------------------------------------------
__global__ __launch_bounds__(256) void norm_kernel(float* __restrict__ out) {
    const int b = blockIdx.x;
    float* __restrict__ row = out + (size_t)b * SS;

    float vals[8];
    float sum = 0.f;
#pragma unroll
    for (int k = 0; k < 8; ++k) {
        vals[k] = row[threadIdx.x + 256 * k];
        sum += vals[k];
    }
#pragma unroll
    for (int off = 32; off >= 1; off >>= 1)
        sum += __shfl_xor(sum, off, 64);

    __shared__ float wsum[4];
    const int lane = threadIdx.x & 63;
    const int wid  = threadIdx.x >> 6;
    if (lane == 0) wsum[wid] = sum;
    __syncthreads();
    const float total = wsum[0] + wsum[1] + wsum[2] + wsum[3];
    const float inv = 1.0f / (total + EPSF);

#pragma unroll
    for (int k = 0; k < 8; ++k)
        row[threadIdx.x + 256 * k] = vals[k] * inv;
}

extern "C" void kernel_launch(void* const* d_in, const int* in_sizes, int n_in,
                              void* d_out, int out_size, void* d_ws, size_t ws_size,
                              hipStream_t stream) {
    const float* x    = (const float*)d_in[0];   // [B,S,D]
    const float* y    = (const float*)d_in[1];   // [B,D]
    const int*   mask = (const int*)d_in[2];     // [B,S]
    const float* M    = (const float*)d_in[3];   // [D,D]
    float* out  = (float*)d_out;                 // [B,S]
    float* proj = (float*)d_ws;                  // [B,D] = 128 KB scratch

    // 32*1024 waves, 4 waves/block
    proj_kernel<<<(BB * DD) / 4, 256, 0, stream>>>(y, M, proj);
    // 32*2048 waves, 4 waves/block
    score_kernel<<<(BB * SS) / 4, 256, 0, stream>>>(x, mask, proj, out);
    // one block per batch
    norm_kernel<<<BB, 256, 0, stream>>>(out);
}

// Round 3
// 327.329 us; speedup vs baseline: 1.0501x; 1.0501x over previous
//
#include <hip/hip_runtime.h>
#include <math.h>

// Problem constants (B,S,D fixed by the reference harness)
#define BB 32
#define SS 2048
#define DD 1024
#define EPSF 1e-7f

// native vector type: accepted by __builtin_nontemporal_load (HIP float4 is not)
typedef float vfloat4 __attribute__((ext_vector_type(4)));

// ---------------------------------------------------------------------------
// Kernel 1: proj[b,e] = sum_d y[b,d] * M[e,d]
// Grid 512 blocks x 256 threads. Block = (4 e-rows) x (16 batches).
// 16 y-rows (64 KB) staged in LDS -> M is read only 2x total (8 MB HBM)
// instead of 32x (128 MB) in the wave-per-(b,e) version.
// ---------------------------------------------------------------------------
__global__ __launch_bounds__(256) void proj_kernel(const float* __restrict__ y,
                                                   const float* __restrict__ M,
                                                   float* __restrict__ proj) {
    __shared__ vfloat4 yl[16 * 256];         // 16 batches x 1024 floats = 64 KB
    const int eg  = blockIdx.x >> 1;         // 0..255 -> e-group of 4 rows
    const int bh  = blockIdx.x & 1;          // batch half: b in [16*bh, 16*bh+16)
    const int tid = threadIdx.x;

    // cooperative load of 16 contiguous y rows (64 KB), fully coalesced
    const vfloat4* __restrict__ ysrc = (const vfloat4*)(y + (size_t)bh * 16 * DD);
#pragma unroll
    for (int k = 0; k < 16; ++k)
        yl[tid + 256 * k] = ysrc[tid + 256 * k];
    __syncthreads();

    const int wave = tid >> 6;
    const int lane = tid & 63;
    const int e = eg * 4 + wave;             // 0..1023

    const vfloat4* __restrict__ Mrow = (const vfloat4*)(M + (size_t)e * DD);
    vfloat4 m[4];
#pragma unroll
    for (int k = 0; k < 4; ++k)
        m[k] = Mrow[lane + 64 * k];          // lane holds 16 floats of M[e,:]

    for (int b = 0; b < 16; ++b) {
        float acc = 0.f;
#pragma unroll
        for (int k = 0; k < 4; ++k) {
            const vfloat4 yv = yl[b * 256 + lane + 64 * k];  // conflict-free b128
            acc += m[k].x * yv.x + m[k].y * yv.y + m[k].z * yv.z + m[k].w * yv.w;
        }
#pragma unroll
        for (int off = 32; off >= 1; off >>= 1)
            acc += __shfl_xor(acc, off, 64);
        if (lane == 0)
            proj[(size_t)(bh * 16 + b) * DD + e] = acc;
    }
}

// ---------------------------------------------------------------------------
// Kernel 2: t[b,s] = mask ? exp(tanh(sum_d x[b,s,d]*proj[b,d])) : 0
// One wave per TWO consecutive rows: proj fragment loaded once and reused,
// masks read as one int2, 2x the x-load ILP, nontemporal x (read-once data,
// keep L2/L3 for proj/mask). Masked rows skip their 4 KB x read entirely.
// ---------------------------------------------------------------------------
__global__ __launch_bounds__(256) void score_kernel(const float* __restrict__ x,
                                                    const int* __restrict__ mask,
                                                    const float* __restrict__ proj,
                                                    float* __restrict__ t) {
    const int wave = (blockIdx.x * 256 + threadIdx.x) >> 6;   // 0..32767
    const int lane = threadIdx.x & 63;
    const int b  = wave >> 10;               // 1024 waves per batch
    const int s0 = (wave & 1023) << 1;       // even row index
    const size_t base = (size_t)b * SS + s0;

    const int2 mm = *(const int2*)(mask + base);   // 8B-aligned (s0 even)
    if ((mm.x | mm.y) == 0) {
        if (lane == 0) { t[base] = 0.f; t[base + 1] = 0.f; }
        return;
    }

    const vfloat4* __restrict__ pr = (const vfloat4*)(proj + (size_t)b * DD);
    vfloat4 p[4];
#pragma unroll
    for (int k = 0; k < 4; ++k)
        p[k] = pr[lane + 64 * k];

    const vfloat4* __restrict__ x0 = (const vfloat4*)(x + base * (size_t)DD);
    const vfloat4* __restrict__ x1 = x0 + 256;

    float acc0 = 0.f, acc1 = 0.f;
    if (mm.x) {                               // wave-uniform branch
#pragma unroll
        for (int k = 0; k < 4; ++k) {
            const vfloat4 xv = __builtin_nontemporal_load(&x0[lane + 64 * k]);
            acc0 += xv.x * p[k].x + xv.y * p[k].y + xv.z * p[k].z + xv.w * p[k].w;
        }
    }
    if (mm.y) {
#pragma unroll
        for (int k = 0; k < 4; ++k) {
            const vfloat4 xv = __builtin_nontemporal_load(&x1[lane + 64 * k]);
            acc1 += xv.x * p[k].x + xv.y * p[k].y + xv.z * p[k].z + xv.w * p[k].w;
        }
    }
#pragma unroll
    for (int off = 32; off >= 1; off >>= 1) {
        acc0 += __shfl_xor(acc0, off, 64);
        acc1 += __shfl_xor(acc1, off, 64);
    }
    if (lane == 0) {
        t[base]     = mm.x ? expf(tanhf(acc0)) : 0.f;
        t[base + 1] = mm.y ? expf(tanhf(acc1)) : 0.f;
    }
}

// ---------------------------------------------------------------------------
// Kernel 3: in-place normalize: out[b,s] /= (sum_s out[b,s] + EPS)
// One block (256 threads) per batch; 8 values/thread held in registers.
// ---------------------------------------------------------------------------
__global__ __launch_bounds__(256) void norm_kernel(float* __restrict__ out) {
    const int b = blockIdx.x;
    float* __restrict__ row = out + (size_t)b * SS;

    float vals[8];
    float sum = 0.f;
#pragma unroll
    for (int k = 0; k < 8; ++k) {
        vals[k] = row[threadIdx.x + 256 * k];
        sum += vals[k];
    }
#pragma unroll
    for (int off = 32; off >= 1; off >>= 1)
        sum += __shfl_xor(sum, off, 64);

    __shared__ float wsum[4];
    const int lane = threadIdx.x & 63;
    const int wid  = threadIdx.x >> 6;
    if (lane == 0) wsum[wid] = sum;
    __syncthreads();
    const float total = wsum[0] + wsum[1] + wsum[2] + wsum[3];
    const float inv = 1.0f / (total + EPSF);

#pragma unroll
    for (int k = 0; k < 8; ++k)
        row[threadIdx.x + 256 * k] = vals[k] * inv;
}

extern "C" void kernel_launch(void* const* d_in, const int* in_sizes, int n_in,
                              void* d_out, int out_size, void* d_ws, size_t ws_size,
                              hipStream_t stream) {
    const float* x    = (const float*)d_in[0];   // [B,S,D]
    const float* y    = (const float*)d_in[1];   // [B,D]
    const int*   mask = (const int*)d_in[2];     // [B,S]
    const float* M    = (const float*)d_in[3];   // [D,D]
    float* out  = (float*)d_out;                 // [B,S]
    float* proj = (float*)d_ws;                  // [B,D] = 128 KB scratch

    // 512 blocks: 256 e-groups x 2 batch-halves
    proj_kernel<<<512, 256, 0, stream>>>(y, M, proj);
    // 32768 waves (2 rows each), 4 waves/block
    score_kernel<<<(BB * SS / 2) / 4, 256, 0, stream>>>(x, mask, proj, out);
    // one block per batch
    norm_kernel<<<BB, 256, 0, stream>>>(out);
}

// Round 4
// 326.330 us; speedup vs baseline: 1.0533x; 1.0031x over previous
//
#include <hip/hip_runtime.h>
#include <math.h>

// Problem constants (B,S,D fixed by the reference harness)
#define BB 32
#define SS 2048
#define DD 1024
#define EPSF 1e-7f

// native vector type: accepted by __builtin_nontemporal_load (HIP float4 is not)
typedef float vfloat4 __attribute__((ext_vector_type(4)));

// ---------------------------------------------------------------------------
// Kernel 1: proj[b,e] = sum_d y[b,d] * M[e,d]
// Grid 512 blocks x 256 threads. Block = (4 e-rows) x (16 batches).
// 16 y-rows (64 KB) staged in LDS -> M read ~2x total (8 MB HBM).
// b-loop fully unrolled: 16 independent reduce chains interleave instead of
// serializing 16 x (6-deep shuffle chain).
// ---------------------------------------------------------------------------
__global__ __launch_bounds__(256) void proj_kernel(const float* __restrict__ y,
                                                   const float* __restrict__ M,
                                                   float* __restrict__ proj) {
    __shared__ vfloat4 yl[16 * 256];         // 16 batches x 1024 floats = 64 KB
    const int eg  = blockIdx.x >> 1;         // 0..255 -> e-group of 4 rows
    const int bh  = blockIdx.x & 1;          // batch half: b in [16*bh, 16*bh+16)
    const int tid = threadIdx.x;

    // cooperative load of 16 contiguous y rows (64 KB), fully coalesced
    const vfloat4* __restrict__ ysrc = (const vfloat4*)(y + (size_t)bh * 16 * DD);
#pragma unroll
    for (int k = 0; k < 16; ++k)
        yl[tid + 256 * k] = ysrc[tid + 256 * k];
    __syncthreads();

    const int wave = tid >> 6;
    const int lane = tid & 63;
    const int e = eg * 4 + wave;             // 0..1023

    const vfloat4* __restrict__ Mrow = (const vfloat4*)(M + (size_t)e * DD);
    vfloat4 m[4];
#pragma unroll
    for (int k = 0; k < 4; ++k)
        m[k] = Mrow[lane + 64 * k];          // lane holds 16 floats of M[e,:]

    float acc[16];
#pragma unroll
    for (int b = 0; b < 16; ++b) {
        float a = 0.f;
#pragma unroll
        for (int k = 0; k < 4; ++k) {
            const vfloat4 yv = yl[b * 256 + lane + 64 * k];  // conflict-free b128
            a += m[k].x * yv.x + m[k].y * yv.y + m[k].z * yv.z + m[k].w * yv.w;
        }
        acc[b] = a;
    }
    // 16 independent butterfly reductions, interleaved
#pragma unroll
    for (int off = 32; off >= 1; off >>= 1) {
#pragma unroll
        for (int b = 0; b < 16; ++b)
            acc[b] += __shfl_xor(acc[b], off, 64);
    }
    if (lane == 0) {
#pragma unroll
        for (int b = 0; b < 16; ++b)
            proj[(size_t)(bh * 16 + b) * DD + e] = acc[b];
    }
}

// ---------------------------------------------------------------------------
// Kernel 2: t[b,s] = mask ? exp(tanh(sum_d x[b,s,d]*proj[b,d])) : 0
// One wave per FOUR consecutive rows: one int4 mask broadcast, proj fragment
// loaded once per 16 KB of x, up to 16 x-loads in flight, 4 independent
// reduce chains, coalesced float4 output store. Per-row mask skip keeps the
// ~50% x-read savings; nontemporal x (read-once) preserves L2/L3 for proj.
// ---------------------------------------------------------------------------
__global__ __launch_bounds__(256) void score_kernel(const float* __restrict__ x,
                                                    const int* __restrict__ mask,
                                                    const float* __restrict__ proj,
                                                    float* __restrict__ t) {
    const int wave = (blockIdx.x * 256 + threadIdx.x) >> 6;   // 0..16383
    const int lane = threadIdx.x & 63;
    const int b  = wave >> 9;                // 512 waves per batch
    const int s0 = (wave & 511) << 2;        // row index, multiple of 4
    const size_t base = (size_t)b * SS + s0;

    const int4 mm = *(const int4*)(mask + base);   // 16B-aligned broadcast
    const int msk[4] = {mm.x, mm.y, mm.z, mm.w};
    if ((mm.x | mm.y | mm.z | mm.w) == 0) {
        if (lane == 0) {
            vfloat4 z; z.x = 0.f; z.y = 0.f; z.z = 0.f; z.w = 0.f;
            *(vfloat4*)(t + base) = z;
        }
        return;
    }

    const vfloat4* __restrict__ pr = (const vfloat4*)(proj + (size_t)b * DD);
    vfloat4 p[4];
#pragma unroll
    for (int k = 0; k < 4; ++k)
        p[k] = pr[lane + 64 * k];

    const vfloat4* __restrict__ x0 = (const vfloat4*)(x + base * (size_t)DD);

    float acc[4] = {0.f, 0.f, 0.f, 0.f};
#pragma unroll
    for (int r = 0; r < 4; ++r) {
        if (msk[r]) {                          // wave-uniform branch
#pragma unroll
            for (int k = 0; k < 4; ++k) {
                const vfloat4 xv =
                    __builtin_nontemporal_load(&x0[r * 256 + lane + 64 * k]);
                acc[r] += xv.x * p[k].x + xv.y * p[k].y +
                          xv.z * p[k].z + xv.w * p[k].w;
            }
        }
    }
    // 4 independent butterfly reductions, interleaved
#pragma unroll
    for (int off = 32; off >= 1; off >>= 1) {
#pragma unroll
        for (int r = 0; r < 4; ++r)
            acc[r] += __shfl_xor(acc[r], off, 64);
    }
    if (lane == 0) {
        vfloat4 o;
        o.x = msk[0] ? expf(tanhf(acc[0])) : 0.f;
        o.y = msk[1] ? expf(tanhf(acc[1])) : 0.f;
        o.z = msk[2] ? expf(tanhf(acc[2])) : 0.f;
        o.w = msk[3] ? expf(tanhf(acc[3])) : 0.f;
        *(vfloat4*)(t + base) = o;             // coalesced 16B store
    }
}

// ---------------------------------------------------------------------------
// Kernel 3: in-place normalize: out[b,s] /= (sum_s out[b,s] + EPS)
// One block (256 threads) per batch; 8 values/thread held in registers.
// ---------------------------------------------------------------------------
__global__ __launch_bounds__(256) void norm_kernel(float* __restrict__ out) {
    const int b = blockIdx.x;
    float* __restrict__ row = out + (size_t)b * SS;

    float vals[8];
    float sum = 0.f;
#pragma unroll
    for (int k = 0; k < 8; ++k) {
        vals[k] = row[threadIdx.x + 256 * k];
        sum += vals[k];
    }
#pragma unroll
    for (int off = 32; off >= 1; off >>= 1)
        sum += __shfl_xor(sum, off, 64);

    __shared__ float wsum[4];
    const int lane = threadIdx.x & 63;
    const int wid  = threadIdx.x >> 6;
    if (lane == 0) wsum[wid] = sum;
    __syncthreads();
    const float total = wsum[0] + wsum[1] + wsum[2] + wsum[3];
    const float inv = 1.0f / (total + EPSF);

#pragma unroll
    for (int k = 0; k < 8; ++k)
        row[threadIdx.x + 256 * k] = vals[k] * inv;
}

extern "C" void kernel_launch(void* const* d_in, const int* in_sizes, int n_in,
                              void* d_out, int out_size, void* d_ws, size_t ws_size,
                              hipStream_t stream) {
    const float* x    = (const float*)d_in[0];   // [B,S,D]
    const float* y    = (const float*)d_in[1];   // [B,D]
    const int*   mask = (const int*)d_in[2];     // [B,S]
    const float* M    = (const float*)d_in[3];   // [D,D]
    float* out  = (float*)d_out;                 // [B,S]
    float* proj = (float*)d_ws;                  // [B,D] = 128 KB scratch

    // 512 blocks: 256 e-groups x 2 batch-halves
    proj_kernel<<<512, 256, 0, stream>>>(y, M, proj);
    // 16384 waves (4 rows each), 4 waves/block
    score_kernel<<<(BB * SS / 4) / 4, 256, 0, stream>>>(x, mask, proj, out);
    // one block per batch
    norm_kernel<<<BB, 256, 0, stream>>>(out);
}